// Round 10
// baseline (443.801 us; speedup 1.0000x reference)
//
#include <hip/hip_runtime.h>
#include <hip/hip_fp16.h>
#include <stdint.h>

// SNNClassifier: B=16384, F=256, H=256, C=10, T=100
// Phase 1: layer-1 LIF spike bitmask into d_ws, QUAD-MAJOR layout:
//   row(b) = 32B; u64 word q (offset 8q) holds halfword s = spikes
//   f in [s*64 + q*16, +16). Built from the 4 seg-ballots with SALU only
//   (ballots are wave-uniform SGPRs; regroup is free, co-issued).
// Phase 2: persistent-state fused kernel, int8 fused-digit GEMM:
//   W*2^14 = a*64 + b (i8 digits); h = (sum a*(64z) + b*z)*2^-14 via
//   mfma_i32_16x16x64_i8, single exact i32 accumulator.
//
// R10 (R9 lesson: per-plane kloops doubled LDS traffic, 614K cyc/CU ~=
// the 331us span -> LDS+latency governs. R8 profile: 73% busy incl MFMA,
// ~30% idle = memory-latency stalls; Z is L3-resident not L2 (52MB vs
// 4MB/XCD) and its loads were under-covered and 4x over-fetched):
//  1. Quad-major Z: lane loads exactly its 8B (1 dwordx2 per t-plane);
//     fetch/tg halves, select chain shrinks to cndmask+shift.
//  2. Double-buffered Z prefetch: manual 2x tg body, loads issue one full
//     kloop (~2600 cyc) before use -> waitcnt free. Raw buffering: +8 VGPR.
//  3. Everything else byte-identical to R8 (276us best).
// Integer acc + identical FP order => absmax must stay EXACTLY 0.003417969.

#define BB 16384
#define FF 256
#define HH 256
#define CC 10
#define TT 100

typedef __attribute__((ext_vector_type(4))) int int4v;

// ---------------- kernel 1: layer-1 spike bitmask ----------------
// Wave owns TWO b: 8 states/thread (jb<2 x js<4). Ballots regrouped to
// quad-major u64s in SALU; lanes 0..7 store 64B contiguous per t,
// batched 4 t at a time.
__global__ __launch_bounds__(256) void spike_gen(
    const float* __restrict__ x, unsigned long long* __restrict__ Z) {
  const int lane = threadIdx.x & 63;
  const int wv   = threadIdx.x >> 6;
  const int b0   = blockIdx.x * 8 + wv * 2;
  const float K_VM = (float)(0.001 * 100.0);        // 0.1f, numpy-exact
  const float K_ID = (float)(1.0 - 0.001 * 200.0);  // 0.8f, numpy-exact

  float v[8], cur[8], xv[8];
#pragma unroll
  for (int jb = 0; jb < 2; ++jb)
#pragma unroll
    for (int js = 0; js < 4; ++js) {
      const int idx = jb * 4 + js;
      xv[idx] = x[(size_t)(b0 + jb) * FF + js * 64 + lane];
      v[idx] = 0.0f; cur[idx] = 0.0f;
    }

  const bool s0 = (lane & 1) != 0, s1 = (lane & 2) != 0, s2 = (lane & 4) != 0;
  // lane L (<8) stores word L of the 2-row 64B group at Z + b0*32
  unsigned long long* zp = Z + (size_t)b0 * 4;

  for (int t4 = 0; t4 < TT; t4 += 4) {
    unsigned long long mq[4];
#pragma unroll
    for (int k = 0; k < 4; ++k) {
      unsigned long long bal[8];
#pragma unroll
      for (int idx = 0; idx < 8; ++idx) {
        float vd   = __fadd_rn(v[idx], __fmul_rn(K_VM, __fadd_rn(-v[idx], cur[idx])));
        float idec = __fmul_rn(cur[idx], K_ID);
        bool z = (vd > 1.0f);
        bal[idx] = __ballot(z);
        v[idx]   = z ? 0.0f : vd;
        cur[idx] = __fadd_rn(idec, xv[idx]);
      }
      // SALU regroup: W[jb*4+q] = quad-major word q of row b0+jb
      unsigned long long W[8];
#pragma unroll
      for (int jb = 0; jb < 2; ++jb) {
        unsigned long long a0 = bal[jb * 4 + 0], a1 = bal[jb * 4 + 1];
        unsigned long long a2 = bal[jb * 4 + 2], a3 = bal[jb * 4 + 3];
#pragma unroll
        for (int q = 0; q < 4; ++q) {
          W[jb * 4 + q] = ((a0 >> (16 * q)) & 0xffffull)
                        | (((a1 >> (16 * q)) & 0xffffull) << 16)
                        | (((a2 >> (16 * q)) & 0xffffull) << 32)
                        | (((a3 >> (16 * q)) & 0xffffull) << 48);
        }
      }
      // 3-level select tree: lane L (<8) picks W[L]
      unsigned long long m0 = s0 ? W[1] : W[0];
      unsigned long long m1 = s0 ? W[3] : W[2];
      unsigned long long m2 = s0 ? W[5] : W[4];
      unsigned long long m3 = s0 ? W[7] : W[6];
      unsigned long long n0 = s1 ? m1 : m0;
      unsigned long long n1 = s1 ? m3 : m2;
      mq[k] = s2 ? n1 : n0;
    }
    if (lane < 8) {
#pragma unroll
      for (int k = 0; k < 4; ++k)
        zp[(size_t)(t4 + k) * (BB * 4) + lane] = mq[k];
    }
  }
}

// ---------------- kernel 2: fused temporal loop (i8) ----------------
// grid: 1024 blocks = 256 bc x 4 hc. block = 256 thr = 4 waves = 4
// b-subtiles of 16 rows; all waves share one 64-h chunk (nt=4).
// LDS slab 32KB: 32 blocks of 1024B, index (nt*2+d)*4+s, content byte
// [lane*16+i] = digit d of W[h0+nt*16+(lane&15)][s*64+(lane>>4)*16+i].
__global__ __launch_bounds__(256, 4) void snn_main(
    const uint32_t* __restrict__ Z, const float* __restrict__ Wh,
    const float* __restrict__ bh, const float* __restrict__ Wr,
    const float* __restrict__ br, float* __restrict__ out) {
  __shared__ __align__(16) char WS[32768];

  const int tid = threadIdx.x;
  const int bx  = blockIdx.x;
  const int hc  = bx & 3;
  const int bc  = bx >> 2;
  const int h0  = hc * 64;
  const int b0  = bc * 64;

  // ---- stage W -> LDS as i8 digit pair, MFMA-fragment order ----
  {
    int4v* ws4 = (int4v*)WS;
#pragma unroll
    for (int half = 0; half < 4; ++half) {
      const int u  = tid + half * 256;
      const int rr = u >> 4;
      const int q  = u & 15;
      const int s  = q >> 2, kq = q & 3;
      const int nt = rr >> 4, n = rr & 15;
      const float* wp = Wh + (size_t)(h0 + rr) * FF + s * 64 + kq * 16;
      uint32_t pa[4], pb[4];
#pragma unroll
      for (int c4 = 0; c4 < 4; ++c4) {
        float4 w4 = *(const float4*)(wp + c4 * 4);
        float wf[4] = {w4.x, w4.y, w4.z, w4.w};
        uint32_t ua = 0, ub = 0;
#pragma unroll
        for (int e = 0; e < 4; ++e) {
          float af = rintf(wf[e] * 256.0f);
          af = fminf(fmaxf(af, -127.0f), 127.0f);
          float bf = rintf(__builtin_fmaf(af, -64.0f, wf[e] * 16384.0f));
          bf = fminf(fmaxf(bf, -127.0f), 127.0f);
          ua |= ((uint32_t)((int)af) & 255u) << (8 * e);
          ub |= ((uint32_t)((int)bf) & 255u) << (8 * e);
        }
        pa[c4] = ua; pb[c4] = ub;
      }
      ws4[((nt * 2 + 0) * 4 + s) * 64 + kq * 16 + n] = *(int4v*)pa;
      ws4[((nt * 2 + 1) * 4 + s) * 64 + kq * 16 + n] = *(int4v*)pb;
    }
  }
  __syncthreads();

  const int lane = tid & 63;
  const int bsub = tid >> 6;
  const int col  = lane & 15;
  const int quad = lane >> 4;

  const int brow = b0 + bsub * 16 + col;

  const float K_VM = (float)(0.001 * 100.0);
  const float K_ID = (float)(1.0 - 0.001 * 200.0);

  float v2[4][4], ii[4][4];
  uint32_t sc[4];  // packed: byte r of sc[nt] = spike count (<=100)
#pragma unroll
  for (int nt = 0; nt < 4; ++nt) {
    sc[nt] = 0u;
#pragma unroll
    for (int r = 0; r < 4; ++r) { v2[nt][r] = 0.f; ii[nt][r] = 0.f; }
  }

  float bias[4];
#pragma unroll
  for (int nt = 0; nt < 4; ++nt) bias[nt] = bh[h0 + nt * 16 + col];

  // quad-major Z: this lane's 8B window of row brow
  const char* zq = (const char*)Z + (size_t)brow * 32 + quad * 8;
  // zr[buf][j] = raw u64 (as uint2) for t-plane j of a tg
  uint2 zrA[2], zrB[2];

  auto load_z = [&](int tgi, uint2 (&zr)[2]) {
#pragma unroll
    for (int j = 0; j < 2; ++j)
      zr[j] = *(const uint2*)(zq + ((size_t)tgi * 2 + j) * (size_t)(BB * 32));
  };
  load_z(0, zrA);

  const char* wsl = WS + lane * 16;

  int4v acc[2][4];

  // one tg (2 t-planes): K loop + LIF, using raw Z words zr
  auto body = [&](const uint2 (&zr)[2]) {
#pragma unroll
    for (int j = 0; j < 2; ++j)
#pragma unroll
      for (int nt = 0; nt < 4; ++nt)
        acc[j][nt] = (int4v){0, 0, 0, 0};

#pragma unroll 1
    for (int s = 0; s < 4; ++s) {
      const int4v* bp = (const int4v*)(wsl + s * 1024);
      int4v Ba[4], Bb[4];
#pragma unroll
      for (int nt = 0; nt < 4; ++nt) {
        Ba[nt] = bp[(nt * 2 + 0) * 256];  // imm offset (nt*2+d)*4096 B
        Bb[nt] = bp[(nt * 2 + 1) * 256];
      }
      const uint32_t sh = (uint32_t)(s & 1) * 16;
#pragma unroll
      for (int j = 0; j < 2; ++j) {
        uint32_t w   = (s & 2) ? zr[j].y : zr[j].x;
        uint32_t h16 = w >> sh;
        int4v za, zb_;
#pragma unroll
        for (int p = 0; p < 4; ++p) {
          uint32_t nib = (h16 >> (4 * p)) & 15u;
          uint32_t zbyte = __umul24(nib, 0x204081u) & 0x01010101u;
          zb_[p] = (int)zbyte;
          za[p]  = (int)(zbyte << 6);  // 64*z, fits i8
        }
#pragma unroll
        for (int nt = 0; nt < 4; ++nt) {
          acc[j][nt] = __builtin_amdgcn_mfma_i32_16x16x64_i8(
              za, Ba[nt], acc[j][nt], 0, 0, 0);
          acc[j][nt] = __builtin_amdgcn_mfma_i32_16x16x64_i8(
              zb_, Bb[nt], acc[j][nt], 0, 0, 0);
        }
      }
    }

    // ---- 2 sequential layer-2 LIF updates (numpy op order) ----
#pragma unroll
    for (int j = 0; j < 2; ++j) {
#pragma unroll
      for (int nt = 0; nt < 4; ++nt) {
#pragma unroll
        for (int r = 0; r < 4; ++r) {
          float h  = __builtin_fmaf((float)acc[j][nt][r], 6.103515625e-05f,
                                    bias[nt]);
          float vv = v2[nt][r], ci = ii[nt][r];
          float vd   = __fadd_rn(vv, __fmul_rn(K_VM, __fadd_rn(-vv, ci)));
          float idec = __fmul_rn(ci, K_ID);
          bool z = (vd > 1.0f);
          v2[nt][r] = z ? 0.0f : vd;
          ii[nt][r] = __fadd_rn(idec, h);
          sc[nt] += (z ? 1u : 0u) << (8 * r);
        }
      }
    }
  };

  // manual 2x software pipeline: prefetch next tg's Z at the top of each
  // half-body; the consuming kloop runs one full tg later -> waits free.
#pragma unroll 1
  for (int it = 0; it < TT / 4; ++it) {
    load_z(2 * it + 1, zrB);      // prefetch for half B
    body(zrA);                    // tg = 2*it
    if (it < TT / 4 - 1) load_z(2 * it + 2, zrA);  // prefetch next half A
    body(zrB);                    // tg = 2*it + 1
  }

  // ---- epilogue: readout GEMM, fused ----
  float mean[4][4];
#pragma unroll
  for (int nt = 0; nt < 4; ++nt)
#pragma unroll
    for (int r = 0; r < 4; ++r)
      mean[nt][r] = __fdiv_rn((float)((sc[nt] >> (8 * r)) & 255u), 100.0f);

#pragma unroll 1
  for (int c = 0; c < CC; ++c) {
    float wc[4];
#pragma unroll
    for (int nt = 0; nt < 4; ++nt) wc[nt] = Wr[c * HH + h0 + nt * 16 + col];
#pragma unroll
    for (int r = 0; r < 4; ++r) {
      float s = 0.f;
#pragma unroll
      for (int nt = 0; nt < 4; ++nt) s = fmaf(mean[nt][r], wc[nt], s);
      s += __shfl_xor(s, 1);
      s += __shfl_xor(s, 2);
      s += __shfl_xor(s, 4);
      s += __shfl_xor(s, 8);
      if (col == 0) {
        int b = b0 + bsub * 16 + quad * 4 + r;
        float add = s + ((hc == 0) ? br[c] : 0.0f);
        atomicAdd(&out[b * CC + c], add);
      }
    }
  }
}

extern "C" void kernel_launch(void* const* d_in, const int* in_sizes, int n_in,
                              void* d_out, int out_size, void* d_ws, size_t ws_size,
                              hipStream_t stream) {
  const float* x  = (const float*)d_in[0];
  const float* Wh = (const float*)d_in[1];
  const float* bh = (const float*)d_in[2];
  const float* Wr = (const float*)d_in[3];
  const float* br = (const float*)d_in[4];
  float* out = (float*)d_out;

  // workspace: spike bitmask, 100*16384*32B = 52.4 MB (quad-major rows)
  unsigned long long* Z = (unsigned long long*)d_ws;

  hipMemsetAsync(d_out, 0, (size_t)out_size * sizeof(float), stream);
  spike_gen<<<BB / 8, 256, 0, stream>>>(x, Z);
  snn_main<<<1024, 256, 0, stream>>>((const uint32_t*)Z, Wh, bh, Wr, br, out);
}

// Round 11
// 396.134 us; speedup vs baseline: 1.1203x; 1.1203x over previous
//
#include <hip/hip_runtime.h>
#include <hip/hip_fp16.h>
#include <stdint.h>

// SNNClassifier: B=16384, F=256, H=256, C=10, T=100
// Phase 1: layer-1 LIF spike bitmask into d_ws (100 x 16384 x 256 bits).
// Phase 2: persistent-state fused kernel, int8 fused-digit GEMM:
//   W*2^14 = a*64 + b (i8 digits); h = (sum a*(64z) + b*z)*2^-14 via
//   mfma_i32_16x16x64_i8, single exact i32 accumulator.
//
// R11 = R8 (best, 276us) + deterministic PHASE STAGGER.
// R10's quad-major Z regressed (FETCH up, 334MB mystery writes) - reverted.
// Why stagger: a block's 4 waves land one-per-SIMD, so each SIMD hosts
// wave-i of the 4 co-resident BLOCKS - all released from __syncthreads
// into identical streams simultaneously and phase-locked forever: all
// burst MFMAs together (pipe 4x oversubscribed), then all do LIF together
// (pipe idle). Measured span ~= MFMA + VALU sum confirms zero overlap.
// Fix: half the blocks (parity (bx>>5)^(bx>>8), alternating under both
// plausible co-residency strides 32 and 256) peel ONE t-plane first,
// offsetting their MFMA bursts by half a period. Peel/tail reuse the
// 2-plane kloop with a duplicated plane (acc[1] discarded): +64 MFMAs
// (~2%) on staggered waves, zero extra registers, one hot code path.
// Integer acc + identical FP order => absmax must stay EXACTLY 0.003417969.

#define BB 16384
#define FF 256
#define HH 256
#define CC 10
#define TT 100

typedef __attribute__((ext_vector_type(4))) int int4v;

// ---------------- kernel 1: layer-1 spike bitmask ----------------
// Wave owns TWO b: 8 states/thread (jb<2 x js<4). Lanes 0..7 store 8 u64
// = 64B contiguous per t; stores batched 4 t at a time.
__global__ __launch_bounds__(256) void spike_gen(
    const float* __restrict__ x, unsigned long long* __restrict__ Z) {
  const int lane = threadIdx.x & 63;
  const int wv   = threadIdx.x >> 6;
  const int b0   = blockIdx.x * 8 + wv * 2;
  const float K_VM = (float)(0.001 * 100.0);        // 0.1f, numpy-exact
  const float K_ID = (float)(1.0 - 0.001 * 200.0);  // 0.8f, numpy-exact

  float v[8], cur[8], xv[8];
#pragma unroll
  for (int jb = 0; jb < 2; ++jb)
#pragma unroll
    for (int js = 0; js < 4; ++js) {
      const int idx = jb * 4 + js;
      xv[idx] = x[(size_t)(b0 + jb) * FF + js * 64 + lane];
      v[idx] = 0.0f; cur[idx] = 0.0f;
    }

  const bool s0 = (lane & 1) != 0, s1 = (lane & 2) != 0, s2 = (lane & 4) != 0;
  unsigned long long* zp = Z + (size_t)b0 * 4;

  for (int t4 = 0; t4 < TT; t4 += 4) {
    unsigned long long mq[4];  // 4 distinct regs -> stores pipeline
#pragma unroll
    for (int k = 0; k < 4; ++k) {
      unsigned long long bal[8];
#pragma unroll
      for (int idx = 0; idx < 8; ++idx) {
        float vd   = __fadd_rn(v[idx], __fmul_rn(K_VM, __fadd_rn(-v[idx], cur[idx])));
        float idec = __fmul_rn(cur[idx], K_ID);
        bool z = (vd > 1.0f);
        bal[idx] = __ballot(z);
        v[idx]   = z ? 0.0f : vd;
        cur[idx] = __fadd_rn(idec, xv[idx]);
      }
      unsigned long long m0 = s0 ? bal[1] : bal[0];
      unsigned long long m1 = s0 ? bal[3] : bal[2];
      unsigned long long m2 = s0 ? bal[5] : bal[4];
      unsigned long long m3 = s0 ? bal[7] : bal[6];
      unsigned long long n0 = s1 ? m1 : m0;
      unsigned long long n1 = s1 ? m3 : m2;
      mq[k] = s2 ? n1 : n0;
    }
    if (lane < 8) {
#pragma unroll
      for (int k = 0; k < 4; ++k)
        zp[(size_t)(t4 + k) * (BB * 4) + lane] = mq[k];
    }
  }
}

// ---------------- kernel 2: fused temporal loop (i8) ----------------
// grid: 1024 blocks = 256 bc x 4 hc. block = 256 thr = 4 waves = 4
// b-subtiles of 16 rows; all waves share one 64-h chunk (nt=4).
// LDS slab 32KB: 32 blocks of 1024B, index (nt*2+d)*4+s, content byte
// [lane*16+i] = digit d of W[h0+nt*16+(lane&15)][s*64+(lane>>4)*16+i].
__global__ __launch_bounds__(256, 4) void snn_main(
    const uint32_t* __restrict__ Z, const float* __restrict__ Wh,
    const float* __restrict__ bh, const float* __restrict__ Wr,
    const float* __restrict__ br, float* __restrict__ out) {
  __shared__ __align__(16) char WS[32768];

  const int tid = threadIdx.x;
  const int bx  = blockIdx.x;
  const int hc  = bx & 3;
  const int bc  = bx >> 2;
  const int h0  = hc * 64;
  const int b0  = bc * 64;

  // ---- stage W -> LDS as i8 digit pair, MFMA-fragment order ----
  {
    int4v* ws4 = (int4v*)WS;
#pragma unroll
    for (int half = 0; half < 4; ++half) {
      const int u  = tid + half * 256;
      const int rr = u >> 4;
      const int q  = u & 15;
      const int s  = q >> 2, kq = q & 3;
      const int nt = rr >> 4, n = rr & 15;
      const float* wp = Wh + (size_t)(h0 + rr) * FF + s * 64 + kq * 16;
      uint32_t pa[4], pb[4];
#pragma unroll
      for (int c4 = 0; c4 < 4; ++c4) {
        float4 w4 = *(const float4*)(wp + c4 * 4);
        float wf[4] = {w4.x, w4.y, w4.z, w4.w};
        uint32_t ua = 0, ub = 0;
#pragma unroll
        for (int e = 0; e < 4; ++e) {
          float af = rintf(wf[e] * 256.0f);
          af = fminf(fmaxf(af, -127.0f), 127.0f);
          float bf = rintf(__builtin_fmaf(af, -64.0f, wf[e] * 16384.0f));
          bf = fminf(fmaxf(bf, -127.0f), 127.0f);
          ua |= ((uint32_t)((int)af) & 255u) << (8 * e);
          ub |= ((uint32_t)((int)bf) & 255u) << (8 * e);
        }
        pa[c4] = ua; pb[c4] = ub;
      }
      ws4[((nt * 2 + 0) * 4 + s) * 64 + kq * 16 + n] = *(int4v*)pa;
      ws4[((nt * 2 + 1) * 4 + s) * 64 + kq * 16 + n] = *(int4v*)pb;
    }
  }
  __syncthreads();

  const int lane = tid & 63;
  const int bsub = tid >> 6;
  const int col  = lane & 15;
  const int quad = lane >> 4;
  const bool qhi = (quad & 2) != 0;
  const uint32_t shl16 = (quad & 1) * 16;

  const int brow = b0 + bsub * 16 + col;

  const float K_VM = (float)(0.001 * 100.0);
  const float K_ID = (float)(1.0 - 0.001 * 200.0);

  float v2[4][4], ii[4][4];
  uint32_t sc[4];  // packed: byte r of sc[nt] = spike count (<=100)
#pragma unroll
  for (int nt = 0; nt < 4; ++nt) {
    sc[nt] = 0u;
#pragma unroll
    for (int r = 0; r < 4; ++r) { v2[nt][r] = 0.f; ii[nt][r] = 0.f; }
  }

  float bias[4];
#pragma unroll
  for (int nt = 0; nt < 4; ++nt) bias[nt] = bh[h0 + nt * 16 + col];

  // per-lane compacted spike halfwords, hwX[j] for 2 t-planes
  uint32_t hw0[2], hw1[2], hw2[2], hw3[2];
  const uint32_t* zrow = Z + (size_t)brow * 8;

  auto load_plane = [&](int t, int j) {
    const uint32_t* p = zrow + (size_t)t * (size_t)(BB * 8);
    uint4 a = *(const uint4*)p;
    uint4 b4 = *(const uint4*)(p + 4);
    hw0[j] = (qhi ? a.y : a.x) >> shl16;
    hw1[j] = (qhi ? a.w : a.z) >> shl16;
    hw2[j] = (qhi ? b4.y : b4.x) >> shl16;
    hw3[j] = (qhi ? b4.w : b4.z) >> shl16;
  };

  const char* wsl = WS + lane * 16;
  int4v acc[2][4];

  // 2-plane K loop (R8's exact structure: frags shared across planes)
  auto kloop2 = [&]() {
#pragma unroll
    for (int j = 0; j < 2; ++j)
#pragma unroll
      for (int nt = 0; nt < 4; ++nt)
        acc[j][nt] = (int4v){0, 0, 0, 0};
#pragma unroll 1
    for (int s = 0; s < 4; ++s) {
      const int4v* bp = (const int4v*)(wsl + s * 1024);
      int4v Ba[4], Bb[4];
#pragma unroll
      for (int nt = 0; nt < 4; ++nt) {
        Ba[nt] = bp[(nt * 2 + 0) * 256];  // imm offset (nt*2+d)*4096 B
        Bb[nt] = bp[(nt * 2 + 1) * 256];
      }
#pragma unroll
      for (int j = 0; j < 2; ++j) {
        uint32_t t0 = (s & 1) ? hw1[j] : hw0[j];
        uint32_t t1 = (s & 1) ? hw3[j] : hw2[j];
        uint32_t h16 = (s & 2) ? t1 : t0;
        int4v za, zb_;
#pragma unroll
        for (int p = 0; p < 4; ++p) {
          uint32_t nib = (h16 >> (4 * p)) & 15u;
          uint32_t zbyte = __umul24(nib, 0x204081u) & 0x01010101u;
          zb_[p] = (int)zbyte;
          za[p]  = (int)(zbyte << 6);  // 64*z, fits i8
        }
#pragma unroll
        for (int nt = 0; nt < 4; ++nt) {
          acc[j][nt] = __builtin_amdgcn_mfma_i32_16x16x64_i8(
              za, Ba[nt], acc[j][nt], 0, 0, 0);
          acc[j][nt] = __builtin_amdgcn_mfma_i32_16x16x64_i8(
              zb_, Bb[nt], acc[j][nt], 0, 0, 0);
        }
      }
    }
  };

  // one plane's LIF over 16 (nt,r) elements, numpy op order (j literal
  // at every call site -> constant-folded indexing)
  auto lifp = [&](int j) {
#pragma unroll
    for (int nt = 0; nt < 4; ++nt) {
#pragma unroll
      for (int r = 0; r < 4; ++r) {
        float h  = __builtin_fmaf((float)acc[j][nt][r], 6.103515625e-05f,
                                  bias[nt]);
        float vv = v2[nt][r], ci = ii[nt][r];
        float vd   = __fadd_rn(vv, __fmul_rn(K_VM, __fadd_rn(-vv, ci)));
        float idec = __fmul_rn(ci, K_ID);
        bool z = (vd > 1.0f);
        v2[nt][r] = z ? 0.0f : vd;
        ii[nt][r] = __fadd_rn(idec, h);
        sc[nt] += (z ? 1u : 0u) << (8 * r);
      }
    }
  };

  // phase stagger: alternates under both plausible co-residency strides
  const int stag = ((bx >> 5) ^ (bx >> 8)) & 1;

  if (stag) {
    // peel t=0 (plane duplicated into j1; acc[1] discarded)
    load_plane(0, 0); load_plane(0, 1);
    kloop2();
    load_plane(1, 0); load_plane(2, 1);
    lifp(0);                                    // t = 0
#pragma unroll 1
    for (int k = 0; k < 49; ++k) {              // planes (1+2k, 2+2k)
      kloop2();
      if (k < 48) { load_plane(3 + 2 * k, 0); load_plane(4 + 2 * k, 1); }
      else        { load_plane(99, 0);         load_plane(99, 1); }
      lifp(0); lifp(1);
    }
    kloop2();                                   // plane 99 (dup in j1)
    lifp(0);                                    // t = 99
  } else {
    load_plane(0, 0); load_plane(1, 1);
#pragma unroll 1
    for (int k = 0; k < 50; ++k) {              // planes (2k, 2k+1)
      kloop2();
      if (k < 49) { load_plane(2 + 2 * k, 0); load_plane(3 + 2 * k, 1); }
      lifp(0); lifp(1);
    }
  }

  // ---- epilogue: readout GEMM, fused ----
  float mean[4][4];
#pragma unroll
  for (int nt = 0; nt < 4; ++nt)
#pragma unroll
    for (int r = 0; r < 4; ++r)
      mean[nt][r] = __fdiv_rn((float)((sc[nt] >> (8 * r)) & 255u), 100.0f);

#pragma unroll 1
  for (int c = 0; c < CC; ++c) {
    float wc[4];
#pragma unroll
    for (int nt = 0; nt < 4; ++nt) wc[nt] = Wr[c * HH + h0 + nt * 16 + col];
#pragma unroll
    for (int r = 0; r < 4; ++r) {
      float s = 0.f;
#pragma unroll
      for (int nt = 0; nt < 4; ++nt) s = fmaf(mean[nt][r], wc[nt], s);
      s += __shfl_xor(s, 1);
      s += __shfl_xor(s, 2);
      s += __shfl_xor(s, 4);
      s += __shfl_xor(s, 8);
      if (col == 0) {
        int b = b0 + bsub * 16 + quad * 4 + r;
        float add = s + ((hc == 0) ? br[c] : 0.0f);
        atomicAdd(&out[b * CC + c], add);
      }
    }
  }
}

extern "C" void kernel_launch(void* const* d_in, const int* in_sizes, int n_in,
                              void* d_out, int out_size, void* d_ws, size_t ws_size,
                              hipStream_t stream) {
  const float* x  = (const float*)d_in[0];
  const float* Wh = (const float*)d_in[1];
  const float* bh = (const float*)d_in[2];
  const float* Wr = (const float*)d_in[3];
  const float* br = (const float*)d_in[4];
  float* out = (float*)d_out;

  // workspace: spike bitmask, 100*16384*32B = 52.4 MB
  unsigned long long* Z = (unsigned long long*)d_ws;

  hipMemsetAsync(d_out, 0, (size_t)out_size * sizeof(float), stream);
  spike_gen<<<BB / 8, 256, 0, stream>>>(x, Z);
  snn_main<<<1024, 256, 0, stream>>>((const uint32_t*)Z, Wh, bh, Wr, br, out);
}